// Round 1
// baseline (199.739 us; speedup 1.0000x reference)
//
#include <hip/hip_runtime.h>
#include <hip/hip_bf16.h>

#define S_LEN 1024
#define DMODEL 1024
#define N_HEADS 16
#define D_HEAD 64
#define BATCH 2
#define N_BH 32

typedef __attribute__((ext_vector_type(8))) short short8;
typedef __attribute__((ext_vector_type(4))) float f32x4;

static __device__ __forceinline__ unsigned short f2bf(float x) {
    unsigned int u = __float_as_uint(x);
    return (unsigned short)((u + 0x7fffu + ((u >> 16) & 1u)) >> 16);
}

// GEMM: C[n][j] = sum_d A[n][d] * W[j][d] + bias[j]
// A: (M x 1024) f32 row-major. W: (1024 x 1024) f32 row-major (output-row major).
// BM=128, BN=64, BK=32. 256 threads = 4 waves (2x2), wave tile 64x32, frags 4x2.
// outmode 0: bf16 head-major  [(b*16+h)*1024 + s]*64 + dh
// outmode 1: bf16 V-transposed [(b*16+h)*64 + dh]*1024 + s
// outmode 2: f32 flat [n*1024 + j]
__device__ __forceinline__ void gemm_body(const float* __restrict__ A,
                                          const float* __restrict__ W,
                                          const float* __restrict__ bias,
                                          void* __restrict__ outp, int outmode,
                                          int n0, int j0)
{
    __shared__ unsigned short As[128 * 40];   // pad stride 40 bf16 -> <=2-way bank conflict
    __shared__ unsigned short Bs[64 * 40];
    const int t = threadIdx.x;
    const int lane = t & 63, w = t >> 6;
    const int wm = w >> 1, wn = w & 1;
    const int g = lane >> 4, r = lane & 15;

    f32x4 acc[4][2];
#pragma unroll
    for (int mi = 0; mi < 4; ++mi)
#pragma unroll
        for (int ni = 0; ni < 2; ++ni)
            acc[mi][ni] = (f32x4){0.f, 0.f, 0.f, 0.f};

    for (int ks = 0; ks < DMODEL / 32; ++ks) {
        const int k0 = ks * 32;
        __syncthreads();
        // stage A tile 128x32 (f32 -> bf16)
#pragma unroll
        for (int i = 0; i < 4; ++i) {
            int row = (t >> 3) + i * 32;
            int quad = t & 7;
            float4 f = *reinterpret_cast<const float4*>(A + (size_t)(n0 + row) * DMODEL + k0 + quad * 4);
            ushort4 hv = { f2bf(f.x), f2bf(f.y), f2bf(f.z), f2bf(f.w) };
            *reinterpret_cast<ushort4*>(&As[row * 40 + quad * 4]) = hv;
        }
        // stage W tile 64x32 (f32 -> bf16)
#pragma unroll
        for (int i = 0; i < 2; ++i) {
            int row = (t >> 3) + i * 32;
            int quad = t & 7;
            float4 f = *reinterpret_cast<const float4*>(W + (size_t)(j0 + row) * DMODEL + k0 + quad * 4);
            ushort4 hv = { f2bf(f.x), f2bf(f.y), f2bf(f.z), f2bf(f.w) };
            *reinterpret_cast<ushort4*>(&Bs[row * 40 + quad * 4]) = hv;
        }
        __syncthreads();
        short8 af[4], bfr[2];
#pragma unroll
        for (int mi = 0; mi < 4; ++mi)
            af[mi] = *reinterpret_cast<const short8*>(&As[(wm * 64 + mi * 16 + r) * 40 + g * 8]);
#pragma unroll
        for (int ni = 0; ni < 2; ++ni)
            bfr[ni] = *reinterpret_cast<const short8*>(&Bs[(wn * 32 + ni * 16 + r) * 40 + g * 8]);
#pragma unroll
        for (int mi = 0; mi < 4; ++mi)
#pragma unroll
            for (int ni = 0; ni < 2; ++ni)
                acc[mi][ni] = __builtin_amdgcn_mfma_f32_16x16x32_bf16(af[mi], bfr[ni], acc[mi][ni], 0, 0, 0);
    }

    // epilogue: D layout col = lane&15, row = (lane>>4)*4 + t4  [m89-verified]
#pragma unroll
    for (int mi = 0; mi < 4; ++mi) {
#pragma unroll
        for (int ni = 0; ni < 2; ++ni) {
            int col = j0 + wn * 32 + ni * 16 + r;
            float bv = bias[col];
#pragma unroll
            for (int t4 = 0; t4 < 4; ++t4) {
                int n = n0 + wm * 64 + mi * 16 + g * 4 + t4;
                float v = acc[mi][ni][t4] + bv;
                if (outmode == 2) {
                    ((float*)outp)[(size_t)n * DMODEL + col] = v;
                } else {
                    int b_ = n >> 10, s_ = n & 1023;
                    int h_ = col >> 6, dh = col & 63;
                    if (outmode == 0)
                        ((unsigned short*)outp)[((size_t)(b_ * N_HEADS + h_) * S_LEN + s_) * D_HEAD + dh] = f2bf(v);
                    else
                        ((unsigned short*)outp)[((size_t)(b_ * N_HEADS + h_) * D_HEAD + dh) * S_LEN + s_] = f2bf(v);
                }
            }
        }
    }
}

__global__ __launch_bounds__(256) void qkv_kernel(
    const float* __restrict__ qx, const float* __restrict__ kx, const float* __restrict__ vx,
    const float* __restrict__ wq, const float* __restrict__ wk, const float* __restrict__ wv,
    const float* __restrict__ bq, const float* __restrict__ bk, const float* __restrict__ bv,
    unsigned short* Qh, unsigned short* Kh, unsigned short* Vt)
{
    const int z = blockIdx.z;
    const float* A    = (z == 0) ? qx : (z == 1) ? kx : vx;
    const float* W    = (z == 0) ? wq : (z == 1) ? wk : wv;
    const float* bias = (z == 0) ? bq : (z == 1) ? bk : bv;
    void* outp = (z == 0) ? (void*)Qh : (z == 1) ? (void*)Kh : (void*)Vt;
    gemm_body(A, W, bias, outp, (z == 2) ? 1 : 0, blockIdx.x * 128, blockIdx.y * 64);
}

__global__ __launch_bounds__(256) void oproj_kernel(
    const float* __restrict__ attn, const float* __restrict__ wo,
    const float* __restrict__ bo, float* out)
{
    gemm_body(attn, wo, bo, (void*)out, 2, blockIdx.x * 128, blockIdx.y * 64);
}

// Flash-style attention. Grid: (S/64 q-tiles, 32 bh). 256 threads = 4 waves.
// Each wave owns 16 q rows. K-tiles of 64 columns, online softmax.
// Qh/Kh: [bh][s][64] bf16.  Vt: [bh][dh][s] bf16.  attn_out: [b*S+s][dm] f32.
__global__ __launch_bounds__(256) void attn_kernel(
    const unsigned short* __restrict__ Qh, const unsigned short* __restrict__ Kh,
    const unsigned short* __restrict__ Vt, const int* __restrict__ mask,
    const float* __restrict__ shift, float* __restrict__ attn_out)
{
    __shared__ unsigned short Plds[4][16][72];   // per-wave P buffer, stride 72 bf16
    const int qt = blockIdx.x, bh = blockIdx.y;
    const int b_ = bh >> 4, h_ = bh & 15;
    const int t = threadIdx.x, w = t >> 6, lane = t & 63;
    const int g = lane >> 4, r = lane & 15;
    const int q0 = qt * 64 + w * 16;
    const int mrow = bh & (BATCH - 1);   // faithful to torch: mask row = bh % B
    const unsigned short* Qb = Qh + (size_t)bh * S_LEN * D_HEAD;
    const unsigned short* Kb = Kh + (size_t)bh * S_LEN * D_HEAD;
    const unsigned short* Vb = Vt + (size_t)bh * D_HEAD * S_LEN;
    const float* shb = shift + (size_t)bh * S_LEN * S_LEN;
    const int* mp = mask + mrow * S_LEN;

    short8 qf0 = *reinterpret_cast<const short8*>(&Qb[(size_t)(q0 + r) * D_HEAD + g * 8]);
    short8 qf1 = *reinterpret_cast<const short8*>(&Qb[(size_t)(q0 + r) * D_HEAD + 32 + g * 8]);

    int mq[4];
#pragma unroll
    for (int t4 = 0; t4 < 4; ++t4) mq[t4] = mp[q0 + g * 4 + t4];

    float m_run[4], l_run[4];
    f32x4 o_acc[4];
#pragma unroll
    for (int i = 0; i < 4; ++i) { m_run[i] = -1e30f; l_run[i] = 0.f; o_acc[i] = (f32x4){0.f,0.f,0.f,0.f}; }

    for (int kt = 0; kt < S_LEN / 64; ++kt) {
        const int kbase = kt * 64;
        float sc_[4][4];
#pragma unroll
        for (int fn = 0; fn < 4; ++fn) {
            int kcol = kbase + fn * 16 + r;
            short8 kf0 = *reinterpret_cast<const short8*>(&Kb[(size_t)kcol * D_HEAD + g * 8]);
            short8 kf1 = *reinterpret_cast<const short8*>(&Kb[(size_t)kcol * D_HEAD + 32 + g * 8]);
            f32x4 a = (f32x4){0.f,0.f,0.f,0.f};
            a = __builtin_amdgcn_mfma_f32_16x16x32_bf16(qf0, kf0, a, 0, 0, 0);
            a = __builtin_amdgcn_mfma_f32_16x16x32_bf16(qf1, kf1, a, 0, 0, 0);
            int mk = mp[kcol];
#pragma unroll
            for (int t4 = 0; t4 < 4; ++t4) {
                int qrow = q0 + g * 4 + t4;
                float sv = a[t4] * 0.125f + shb[(size_t)qrow * S_LEN + kcol];
                sc_[fn][t4] = (mq[t4] & mk) ? sv : -1e9f;
            }
        }
        // online softmax: rows live in 16-lane groups (xor 1,2,4,8)
        float pexp[4][4], scl[4];
#pragma unroll
        for (int t4 = 0; t4 < 4; ++t4) {
            float mx = fmaxf(fmaxf(sc_[0][t4], sc_[1][t4]), fmaxf(sc_[2][t4], sc_[3][t4]));
            mx = fmaxf(mx, __shfl_xor(mx, 1));
            mx = fmaxf(mx, __shfl_xor(mx, 2));
            mx = fmaxf(mx, __shfl_xor(mx, 4));
            mx = fmaxf(mx, __shfl_xor(mx, 8));
            float mnew = fmaxf(m_run[t4], mx);
            float sc = __expf(m_run[t4] - mnew);
            float rs = 0.f;
#pragma unroll
            for (int fn = 0; fn < 4; ++fn) {
                float p = __expf(sc_[fn][t4] - mnew);
                pexp[fn][t4] = p; rs += p;
            }
            rs += __shfl_xor(rs, 1);
            rs += __shfl_xor(rs, 2);
            rs += __shfl_xor(rs, 4);
            rs += __shfl_xor(rs, 8);
            l_run[t4] = l_run[t4] * sc + rs;
            m_run[t4] = mnew;
            scl[t4] = sc;
        }
#pragma unroll
        for (int df = 0; df < 4; ++df)
#pragma unroll
            for (int t4 = 0; t4 < 4; ++t4) o_acc[df][t4] *= scl[t4];
        // P -> LDS (score layout) then read back in A-operand layout (wave-private)
#pragma unroll
        for (int fn = 0; fn < 4; ++fn)
#pragma unroll
            for (int t4 = 0; t4 < 4; ++t4)
                Plds[w][g * 4 + t4][fn * 16 + r] = f2bf(pexp[fn][t4]);
        asm volatile("s_waitcnt lgkmcnt(0)" ::: "memory");
        __builtin_amdgcn_sched_barrier(0);
        short8 pf0 = *reinterpret_cast<const short8*>(&Plds[w][r][g * 8]);
        short8 pf1 = *reinterpret_cast<const short8*>(&Plds[w][r][32 + g * 8]);
#pragma unroll
        for (int df = 0; df < 4; ++df) {
            short8 vf0 = *reinterpret_cast<const short8*>(&Vb[(size_t)(df * 16 + r) * S_LEN + kbase + g * 8]);
            short8 vf1 = *reinterpret_cast<const short8*>(&Vb[(size_t)(df * 16 + r) * S_LEN + kbase + 32 + g * 8]);
            o_acc[df] = __builtin_amdgcn_mfma_f32_16x16x32_bf16(pf0, vf0, o_acc[df], 0, 0, 0);
            o_acc[df] = __builtin_amdgcn_mfma_f32_16x16x32_bf16(pf1, vf1, o_acc[df], 0, 0, 0);
        }
    }
    // write attn output (f32, [b*S+s][h*64+dh]) for the output projection
#pragma unroll
    for (int df = 0; df < 4; ++df) {
#pragma unroll
        for (int t4 = 0; t4 < 4; ++t4) {
            float v = o_acc[df][t4] / l_run[t4];
            int srow = q0 + g * 4 + t4;
            int col = h_ * D_HEAD + df * 16 + r;
            attn_out[(size_t)(b_ * S_LEN + srow) * DMODEL + col] = v;
        }
    }
}

extern "C" void kernel_launch(void* const* d_in, const int* in_sizes, int n_in,
                              void* d_out, int out_size, void* d_ws, size_t ws_size,
                              hipStream_t stream)
{
    const float* q     = (const float*)d_in[0];
    const float* k     = (const float*)d_in[1];
    const float* v     = (const float*)d_in[2];
    const int*   mask  = (const int*)d_in[3];
    const float* shift = (const float*)d_in[4];
    const float* wq    = (const float*)d_in[5];
    const float* bq    = (const float*)d_in[6];
    const float* wk    = (const float*)d_in[7];
    const float* bk    = (const float*)d_in[8];
    const float* wv    = (const float*)d_in[9];
    const float* bv    = (const float*)d_in[10];
    const float* wo    = (const float*)d_in[11];
    const float* bo    = (const float*)d_in[12];
    float* out = (float*)d_out;

    // workspace: Qh 4MB | Kh 4MB | Vt 4MB | attn f32 8MB  (total 20MB)
    unsigned short* Qh = (unsigned short*)d_ws;
    unsigned short* Kh = Qh + (size_t)N_BH * S_LEN * D_HEAD;
    unsigned short* Vt = Kh + (size_t)N_BH * S_LEN * D_HEAD;
    float* attnbuf = (float*)(Vt + (size_t)N_BH * S_LEN * D_HEAD);

    dim3 blk(256);
    qkv_kernel<<<dim3(16, 16, 3), blk, 0, stream>>>(q, k, v, wq, wk, wv, bq, bk, bv, Qh, Kh, Vt);
    attn_kernel<<<dim3(16, 32), blk, 0, stream>>>(Qh, Kh, Vt, mask, shift, attnbuf);
    oproj_kernel<<<dim3(16, 16), blk, 0, stream>>>(attnbuf, wo, bo, out);
}

// Round 3
// 185.340 us; speedup vs baseline: 1.0777x; 1.0777x over previous
//
#include <hip/hip_runtime.h>
#include <hip/hip_bf16.h>

#define S_LEN 1024
#define DMODEL 1024
#define N_HEADS 16
#define D_HEAD 64
#define BATCH 2
#define N_BH 32

typedef __attribute__((ext_vector_type(8))) short short8;
typedef __attribute__((ext_vector_type(4))) float f32x4;
typedef __attribute__((ext_vector_type(4))) int i32x4;

static __device__ __forceinline__ unsigned short f2bf(float x) {
    unsigned int u = __float_as_uint(x);
    return (unsigned short)((u + 0x7fffu + ((u >> 16) & 1u)) >> 16);
}

static __device__ __forceinline__ f32x4 ldnt4(const float* p) {
    return __builtin_nontemporal_load(reinterpret_cast<const f32x4*>(p));
}

// ---------------- GEMM ----------------
// C[n][j] = sum_d A[n][d] * W[j][d] + bias[j]
// outmode 0: bf16 head-major; 1: bf16 V-transposed; 2: f32 flat
__device__ __forceinline__ void gemm_body(const float* __restrict__ A,
                                          const float* __restrict__ W,
                                          const float* __restrict__ bias,
                                          void* __restrict__ outp, int outmode,
                                          int n0, int j0)
{
    __shared__ unsigned short As[128 * 40];
    __shared__ unsigned short Bs[64 * 40];
    const int t = threadIdx.x;
    const int lane = t & 63, w = t >> 6;
    const int wm = w >> 1, wn = w & 1;
    const int g = lane >> 4, r = lane & 15;

    f32x4 acc[4][2];
#pragma unroll
    for (int mi = 0; mi < 4; ++mi)
#pragma unroll
        for (int ni = 0; ni < 2; ++ni)
            acc[mi][ni] = (f32x4){0.f, 0.f, 0.f, 0.f};

    for (int ks = 0; ks < DMODEL / 32; ++ks) {
        const int k0 = ks * 32;
        __syncthreads();
#pragma unroll
        for (int i = 0; i < 4; ++i) {
            int row = (t >> 3) + i * 32;
            int quad = t & 7;
            float4 f = *reinterpret_cast<const float4*>(A + (size_t)(n0 + row) * DMODEL + k0 + quad * 4);
            ushort4 hv = { f2bf(f.x), f2bf(f.y), f2bf(f.z), f2bf(f.w) };
            *reinterpret_cast<ushort4*>(&As[row * 40 + quad * 4]) = hv;
        }
#pragma unroll
        for (int i = 0; i < 2; ++i) {
            int row = (t >> 3) + i * 32;
            int quad = t & 7;
            float4 f = *reinterpret_cast<const float4*>(W + (size_t)(j0 + row) * DMODEL + k0 + quad * 4);
            ushort4 hv = { f2bf(f.x), f2bf(f.y), f2bf(f.z), f2bf(f.w) };
            *reinterpret_cast<ushort4*>(&Bs[row * 40 + quad * 4]) = hv;
        }
        __syncthreads();
        short8 af[4], bfr[2];
#pragma unroll
        for (int mi = 0; mi < 4; ++mi)
            af[mi] = *reinterpret_cast<const short8*>(&As[(wm * 64 + mi * 16 + r) * 40 + g * 8]);
#pragma unroll
        for (int ni = 0; ni < 2; ++ni)
            bfr[ni] = *reinterpret_cast<const short8*>(&Bs[(wn * 32 + ni * 16 + r) * 40 + g * 8]);
#pragma unroll
        for (int mi = 0; mi < 4; ++mi)
#pragma unroll
            for (int ni = 0; ni < 2; ++ni)
                acc[mi][ni] = __builtin_amdgcn_mfma_f32_16x16x32_bf16(af[mi], bfr[ni], acc[mi][ni], 0, 0, 0);
    }

#pragma unroll
    for (int mi = 0; mi < 4; ++mi) {
#pragma unroll
        for (int ni = 0; ni < 2; ++ni) {
            int col = j0 + wn * 32 + ni * 16 + r;
            float bv = bias[col];
#pragma unroll
            for (int t4 = 0; t4 < 4; ++t4) {
                int n = n0 + wm * 64 + mi * 16 + g * 4 + t4;
                float v = acc[mi][ni][t4] + bv;
                if (outmode == 2) {
                    ((float*)outp)[(size_t)n * DMODEL + col] = v;
                } else {
                    int b_ = n >> 10, s_ = n & 1023;
                    int h_ = col >> 6, dh = col & 63;
                    if (outmode == 0)
                        ((unsigned short*)outp)[((size_t)(b_ * N_HEADS + h_) * S_LEN + s_) * D_HEAD + dh] = f2bf(v);
                    else
                        ((unsigned short*)outp)[((size_t)(b_ * N_HEADS + h_) * D_HEAD + dh) * S_LEN + s_] = f2bf(v);
                }
            }
        }
    }
}

__global__ __launch_bounds__(256) void qkv_kernel(
    const float* __restrict__ qx, const float* __restrict__ kx, const float* __restrict__ vx,
    const float* __restrict__ wq, const float* __restrict__ wk, const float* __restrict__ wv,
    const float* __restrict__ bq, const float* __restrict__ bk, const float* __restrict__ bv,
    unsigned short* Qh, unsigned short* Kh, unsigned short* Vt)
{
    const int z = blockIdx.z;
    const float* A    = (z == 0) ? qx : (z == 1) ? kx : vx;
    const float* W    = (z == 0) ? wq : (z == 1) ? wk : wv;
    const float* bias = (z == 0) ? bq : (z == 1) ? bk : bv;
    void* outp = (z == 0) ? (void*)Qh : (z == 1) ? (void*)Kh : (void*)Vt;
    gemm_body(A, W, bias, outp, (z == 2) ? 1 : 0, blockIdx.x * 128, blockIdx.y * 64);
}

__global__ __launch_bounds__(256) void oproj_kernel(
    const float* __restrict__ attn, const float* __restrict__ wo,
    const float* __restrict__ bo, float* out)
{
    gemm_body(attn, wo, bo, (void*)out, 2, blockIdx.x * 128, blockIdx.y * 64);
}

// ---------------- Attention (swapped-QK, split-K, vectorized shift) ----------------
// Grid: (S/64 q-tiles, 32 bh, nparts). 256 thr = 4 waves, wave owns 16 q-rows.
// Swapped QK^T: S^T = mfma(K_frag, Q_frag). Lane(r,g), reg t4 holds
//   S[kcol = kbase + fn*16 + g*4 + t4][qrow = q0 + r]
// so shift/mask are vector loads and the softmax row lives per-lane.
__global__ __launch_bounds__(256) void attn_kernel(
    const unsigned short* __restrict__ Qh, const unsigned short* __restrict__ Kh,
    const unsigned short* __restrict__ Vt, const int* __restrict__ mask,
    const float* __restrict__ shift, float* __restrict__ opart,
    float* __restrict__ mlpart, int nparts)
{
    __shared__ unsigned short Plds[4][16][72];
    const int qt = blockIdx.x, bh = blockIdx.y, part = blockIdx.z;
    const int t = threadIdx.x, w = t >> 6, lane = t & 63;
    const int g = lane >> 4, r = lane & 15;
    const int q0 = qt * 64 + w * 16;
    const int KP = S_LEN / nparts;
    const int kstart = part * KP;
    const int NT = KP / 64;

    const unsigned short* Qb = Qh + (size_t)bh * S_LEN * D_HEAD;
    const unsigned short* Kb = Kh + (size_t)bh * S_LEN * D_HEAD;
    const unsigned short* Vb = Vt + (size_t)bh * D_HEAD * S_LEN;
    const float* shb = shift + (size_t)bh * S_LEN * S_LEN;
    const int* mp = mask + (bh & (BATCH - 1)) * S_LEN;   // torch tiling: row = bh % B

    // Q fragments (B-operand): lane(r,g) holds Q[q0+r][g*8..g*8+7]
    short8 qf0 = *reinterpret_cast<const short8*>(&Qb[(size_t)(q0 + r) * D_HEAD + g * 8]);
    short8 qf1 = *reinterpret_cast<const short8*>(&Qb[(size_t)(q0 + r) * D_HEAD + 32 + g * 8]);
    const int mq = mp[q0 + r];
    const size_t shrow = (size_t)(q0 + r) * S_LEN;

    float m_run = -1e30f, l_run = 0.f;
    f32x4 o_acc[4];
#pragma unroll
    for (int i = 0; i < 4; ++i) o_acc[i] = (f32x4){0.f, 0.f, 0.f, 0.f};

    // prefetch shift for tile 0
    f32x4 sh[4];
#pragma unroll
    for (int fn = 0; fn < 4; ++fn)
        sh[fn] = ldnt4(shb + shrow + kstart + fn * 16 + g * 4);

    for (int kt = 0; kt < NT; ++kt) {
        const int kbase = kstart + kt * 64;
        f32x4 shc[4];
#pragma unroll
        for (int fn = 0; fn < 4; ++fn) shc[fn] = sh[fn];
        if (kt + 1 < NT) {
#pragma unroll
            for (int fn = 0; fn < 4; ++fn)
                sh[fn] = ldnt4(shb + shrow + kbase + 64 + fn * 16 + g * 4);
        }

        // K fragments (A-operand): lane(r,g) holds K[kbase+fn*16+r][g*8..]
        short8 kf[8];
#pragma unroll
        for (int fn = 0; fn < 4; ++fn) {
            kf[2 * fn]     = *reinterpret_cast<const short8*>(&Kb[(size_t)(kbase + fn * 16 + r) * D_HEAD + g * 8]);
            kf[2 * fn + 1] = *reinterpret_cast<const short8*>(&Kb[(size_t)(kbase + fn * 16 + r) * D_HEAD + 32 + g * 8]);
        }

        float sc[4][4];
#pragma unroll
        for (int fn = 0; fn < 4; ++fn) {
            f32x4 a = (f32x4){0.f, 0.f, 0.f, 0.f};
            a = __builtin_amdgcn_mfma_f32_16x16x32_bf16(kf[2 * fn], qf0, a, 0, 0, 0);
            a = __builtin_amdgcn_mfma_f32_16x16x32_bf16(kf[2 * fn + 1], qf1, a, 0, 0, 0);
            i32x4 mk = *reinterpret_cast<const i32x4*>(mp + kbase + fn * 16 + g * 4);
#pragma unroll
            for (int t4 = 0; t4 < 4; ++t4)
                sc[fn][t4] = (mq & mk[t4]) ? fmaf(a[t4], 0.125f, shc[fn][t4]) : -1e9f;
        }

        // row (q0+r) softmax: 16 local values + cross-group reduce (xor 16, 32)
        float mx = sc[0][0];
#pragma unroll
        for (int fn = 0; fn < 4; ++fn)
#pragma unroll
            for (int t4 = 0; t4 < 4; ++t4) mx = fmaxf(mx, sc[fn][t4]);
        mx = fmaxf(mx, __shfl_xor(mx, 16));
        mx = fmaxf(mx, __shfl_xor(mx, 32));
        float mnew = fmaxf(m_run, mx);
        float scl = __expf(m_run - mnew);
        float rs = 0.f;
        float pexp[4][4];
#pragma unroll
        for (int fn = 0; fn < 4; ++fn)
#pragma unroll
            for (int t4 = 0; t4 < 4; ++t4) {
                float p = __expf(sc[fn][t4] - mnew);
                pexp[fn][t4] = p; rs += p;
            }
        rs += __shfl_xor(rs, 16);
        rs += __shfl_xor(rs, 32);
        l_run = l_run * scl + rs;
        m_run = mnew;

        // move scl to the o_acc row view (row = g*4+t4): source lane = g*16 + (g*4+t4)
        float scl4[4];
#pragma unroll
        for (int t4 = 0; t4 < 4; ++t4)
            scl4[t4] = __shfl(scl, (lane & 48) + ((lane >> 4) & 3) * 4 + t4);
#pragma unroll
        for (int df = 0; df < 4; ++df)
#pragma unroll
            for (int t4 = 0; t4 < 4; ++t4) o_acc[df][t4] *= scl4[t4];

        // P -> LDS: lane(r,g) writes row r, cols fn*16+g*4..+3 (vectorized ushort4)
#pragma unroll
        for (int fn = 0; fn < 4; ++fn) {
            ushort4 pk = { f2bf(pexp[fn][0]), f2bf(pexp[fn][1]), f2bf(pexp[fn][2]), f2bf(pexp[fn][3]) };
            *reinterpret_cast<ushort4*>(&Plds[w][r][fn * 16 + g * 4]) = pk;
        }
        asm volatile("s_waitcnt lgkmcnt(0)" ::: "memory");
        __builtin_amdgcn_sched_barrier(0);
        // P A-operand frags: lane(r,g) holds P[q0+r][kcols g*8..+7] (+32 for pf1)
        short8 pf0 = *reinterpret_cast<const short8*>(&Plds[w][r][g * 8]);
        short8 pf1 = *reinterpret_cast<const short8*>(&Plds[w][r][32 + g * 8]);
#pragma unroll
        for (int df = 0; df < 4; ++df) {
            short8 vf0 = *reinterpret_cast<const short8*>(&Vb[(size_t)(df * 16 + r) * S_LEN + kbase + g * 8]);
            short8 vf1 = *reinterpret_cast<const short8*>(&Vb[(size_t)(df * 16 + r) * S_LEN + kbase + 32 + g * 8]);
            o_acc[df] = __builtin_amdgcn_mfma_f32_16x16x32_bf16(pf0, vf0, o_acc[df], 0, 0, 0);
            o_acc[df] = __builtin_amdgcn_mfma_f32_16x16x32_bf16(pf1, vf1, o_acc[df], 0, 0, 0);
        }
    }

    // store partials: o rows indexed by (g,t4), ml rows per-lane r (g==0 writes)
    const size_t pb = (size_t)(part * N_BH + bh) * S_LEN;
    if (g == 0) {
        float2 ml = { m_run, l_run };
        *reinterpret_cast<float2*>(&mlpart[(pb + q0 + r) * 2]) = ml;
    }
#pragma unroll
    for (int df = 0; df < 4; ++df)
#pragma unroll
        for (int t4 = 0; t4 < 4; ++t4)
            opart[(pb + q0 + g * 4 + t4) * D_HEAD + df * 16 + r] = o_acc[df][t4];
}

// merge split-K partials -> attnbuf f32 [b*S+s][h*64+dh]
__global__ __launch_bounds__(256) void combine_kernel(
    const float* __restrict__ opart, const float* __restrict__ mlpart,
    float* __restrict__ attnbuf, int nparts)
{
    int tid = blockIdx.x * 256 + threadIdx.x;
    int c4 = tid & 15;
    int row = (tid >> 4) & (S_LEN - 1);
    int bh = tid >> 14;
    int b_ = bh >> 4, h_ = bh & 15;

    float mv[4], lv[4];
    float M = -1e30f;
    for (int p = 0; p < nparts; ++p) {
        float2 ml = *reinterpret_cast<const float2*>(&mlpart[((size_t)(p * N_BH + bh) * S_LEN + row) * 2]);
        mv[p] = ml.x; lv[p] = ml.y;
        M = fmaxf(M, ml.x);
    }
    float L = 0.f;
    f32x4 acc = {0.f, 0.f, 0.f, 0.f};
    for (int p = 0; p < nparts; ++p) {
        float e = __expf(mv[p] - M);
        L += lv[p] * e;
        f32x4 o = *reinterpret_cast<const f32x4*>(
            &opart[((size_t)(p * N_BH + bh) * S_LEN + row) * D_HEAD + c4 * 4]);
#pragma unroll
        for (int j = 0; j < 4; ++j) acc[j] += o[j] * e;
    }
    float inv = 1.f / L;
    f32x4 outv = { acc[0] * inv, acc[1] * inv, acc[2] * inv, acc[3] * inv };
    *reinterpret_cast<f32x4*>(&attnbuf[(size_t)(b_ * S_LEN + row) * DMODEL + h_ * D_HEAD + c4 * 4]) = outv;
}

extern "C" void kernel_launch(void* const* d_in, const int* in_sizes, int n_in,
                              void* d_out, int out_size, void* d_ws, size_t ws_size,
                              hipStream_t stream)
{
    const float* q     = (const float*)d_in[0];
    const float* k     = (const float*)d_in[1];
    const float* v     = (const float*)d_in[2];
    const int*   mask  = (const int*)d_in[3];
    const float* shift = (const float*)d_in[4];
    const float* wq    = (const float*)d_in[5];
    const float* bq    = (const float*)d_in[6];
    const float* wk    = (const float*)d_in[7];
    const float* bk    = (const float*)d_in[8];
    const float* wv    = (const float*)d_in[9];
    const float* bv    = (const float*)d_in[10];
    const float* wo    = (const float*)d_in[11];
    const float* bo    = (const float*)d_in[12];
    float* out = (float*)d_out;

    // ws layout: Qh 4MB | Kh 4MB | Vt 4MB | attnbuf 8MB | opart nparts*8MB | mlpart nparts*256KB
    const size_t nhalf = (size_t)N_BH * S_LEN * D_HEAD;   // 2M elems
    unsigned short* Qh = (unsigned short*)d_ws;
    unsigned short* Kh = Qh + nhalf;
    unsigned short* Vt = Kh + nhalf;
    float* attnbuf = (float*)(Vt + nhalf);
    float* opart = attnbuf + (size_t)BATCH * S_LEN * DMODEL;
    const size_t base = 12u * 1024 * 1024 + 8u * 1024 * 1024;
    const size_t per_part = (size_t)N_BH * S_LEN * D_HEAD * 4 + (size_t)N_BH * S_LEN * 2 * 4;
    int nparts = 1;
    if (ws_size >= base + 4 * per_part) nparts = 4;
    else if (ws_size >= base + 2 * per_part) nparts = 2;
    float* mlpart = opart + (size_t)nparts * N_BH * S_LEN * D_HEAD;

    dim3 blk(256);
    qkv_kernel<<<dim3(16, 16, 3), blk, 0, stream>>>(q, k, v, wq, wk, wv, bq, bk, bv, Qh, Kh, Vt);
    attn_kernel<<<dim3(16, 32, nparts), blk, 0, stream>>>(Qh, Kh, Vt, mask, shift, opart, mlpart, nparts);
    combine_kernel<<<dim3((N_BH * S_LEN * 16) / 256), blk, 0, stream>>>(opart, mlpart, attnbuf, nparts);
    oproj_kernel<<<dim3(16, 16), blk, 0, stream>>>(attnbuf, wo, bo, out);
}

// Round 4
// 156.200 us; speedup vs baseline: 1.2787x; 1.1866x over previous
//
#include <hip/hip_runtime.h>
#include <hip/hip_bf16.h>

#define S_LEN 1024
#define DMODEL 1024
#define N_HEADS 16
#define D_HEAD 64
#define BATCH 2
#define N_BH 32

typedef __attribute__((ext_vector_type(8))) short short8;
typedef __attribute__((ext_vector_type(4))) float f32x4;
typedef __attribute__((ext_vector_type(4))) int i32x4;

static __device__ __forceinline__ unsigned short f2bf(float x) {
    unsigned int u = __float_as_uint(x);
    return (unsigned short)((u + 0x7fffu + ((u >> 16) & 1u)) >> 16);
}

static __device__ __forceinline__ f32x4 ldnt4(const float* p) {
    return __builtin_nontemporal_load(reinterpret_cast<const f32x4*>(p));
}

// ---------------- GEMM ----------------
// C[n][j] = sum_d A[n][d] * W[j][d] + bias[j]
// AMODE 0: A is f32. AMODE 1: A is bf16 (row-major, stride DMODEL).
// outmode 0: bf16 head-major; 1: bf16 V-transposed; 2: f32 flat
template <int AMODE>
__device__ __forceinline__ void gemm_body(const void* __restrict__ Araw,
                                          const float* __restrict__ W,
                                          const float* __restrict__ bias,
                                          void* __restrict__ outp, int outmode,
                                          int n0, int j0)
{
    __shared__ unsigned short As[128 * 40];
    __shared__ unsigned short Bs[64 * 40];
    const int t = threadIdx.x;
    const int lane = t & 63, w = t >> 6;
    const int wm = w >> 1, wn = w & 1;
    const int g = lane >> 4, r = lane & 15;

    f32x4 acc[4][2];
#pragma unroll
    for (int mi = 0; mi < 4; ++mi)
#pragma unroll
        for (int ni = 0; ni < 2; ++ni)
            acc[mi][ni] = (f32x4){0.f, 0.f, 0.f, 0.f};

    for (int ks = 0; ks < DMODEL / 32; ++ks) {
        const int k0 = ks * 32;
        __syncthreads();
        if (AMODE == 0) {
            const float* A = (const float*)Araw;
#pragma unroll
            for (int i = 0; i < 4; ++i) {
                int row = (t >> 3) + i * 32;
                int quad = t & 7;
                float4 f = *reinterpret_cast<const float4*>(A + (size_t)(n0 + row) * DMODEL + k0 + quad * 4);
                ushort4 hv = { f2bf(f.x), f2bf(f.y), f2bf(f.z), f2bf(f.w) };
                *reinterpret_cast<ushort4*>(&As[row * 40 + quad * 4]) = hv;
            }
        } else {
            const unsigned short* A = (const unsigned short*)Araw;
#pragma unroll
            for (int i = 0; i < 2; ++i) {
                int row = (t >> 2) + i * 64;
                int seg = t & 3;
                short8 v8 = *reinterpret_cast<const short8*>(A + (size_t)(n0 + row) * DMODEL + k0 + seg * 8);
                *reinterpret_cast<short8*>(&As[row * 40 + seg * 8]) = v8;
            }
        }
#pragma unroll
        for (int i = 0; i < 2; ++i) {
            int row = (t >> 3) + i * 32;
            int quad = t & 7;
            float4 f = *reinterpret_cast<const float4*>(W + (size_t)(j0 + row) * DMODEL + k0 + quad * 4);
            ushort4 hv = { f2bf(f.x), f2bf(f.y), f2bf(f.z), f2bf(f.w) };
            *reinterpret_cast<ushort4*>(&Bs[row * 40 + quad * 4]) = hv;
        }
        __syncthreads();
        short8 af[4], bfr[2];
#pragma unroll
        for (int mi = 0; mi < 4; ++mi)
            af[mi] = *reinterpret_cast<const short8*>(&As[(wm * 64 + mi * 16 + r) * 40 + g * 8]);
#pragma unroll
        for (int ni = 0; ni < 2; ++ni)
            bfr[ni] = *reinterpret_cast<const short8*>(&Bs[(wn * 32 + ni * 16 + r) * 40 + g * 8]);
#pragma unroll
        for (int mi = 0; mi < 4; ++mi)
#pragma unroll
            for (int ni = 0; ni < 2; ++ni)
                acc[mi][ni] = __builtin_amdgcn_mfma_f32_16x16x32_bf16(af[mi], bfr[ni], acc[mi][ni], 0, 0, 0);
    }

#pragma unroll
    for (int mi = 0; mi < 4; ++mi) {
#pragma unroll
        for (int ni = 0; ni < 2; ++ni) {
            int col = j0 + wn * 32 + ni * 16 + r;
            float bv = bias[col];
#pragma unroll
            for (int t4 = 0; t4 < 4; ++t4) {
                int n = n0 + wm * 64 + mi * 16 + g * 4 + t4;
                float v = acc[mi][ni][t4] + bv;
                if (outmode == 2) {
                    ((float*)outp)[(size_t)n * DMODEL + col] = v;
                } else {
                    int b_ = n >> 10, s_ = n & 1023;
                    int h_ = col >> 6, dh = col & 63;
                    if (outmode == 0)
                        ((unsigned short*)outp)[((size_t)(b_ * N_HEADS + h_) * S_LEN + s_) * D_HEAD + dh] = f2bf(v);
                    else
                        ((unsigned short*)outp)[((size_t)(b_ * N_HEADS + h_) * D_HEAD + dh) * S_LEN + s_] = f2bf(v);
                }
            }
        }
    }
}

__global__ __launch_bounds__(256) void qkv_kernel(
    const float* __restrict__ qx, const float* __restrict__ kx, const float* __restrict__ vx,
    const float* __restrict__ wq, const float* __restrict__ wk, const float* __restrict__ wv,
    const float* __restrict__ bq, const float* __restrict__ bk, const float* __restrict__ bv,
    unsigned short* Qh, unsigned short* Kh, unsigned short* Vt)
{
    const int z = blockIdx.z;
    const float* A    = (z == 0) ? qx : (z == 1) ? kx : vx;
    const float* W    = (z == 0) ? wq : (z == 1) ? wk : wv;
    const float* bias = (z == 0) ? bq : (z == 1) ? bk : bv;
    void* outp = (z == 0) ? (void*)Qh : (z == 1) ? (void*)Kh : (void*)Vt;
    gemm_body<0>(A, W, bias, outp, (z == 2) ? 1 : 0, blockIdx.x * 128, blockIdx.y * 64);
}

__global__ __launch_bounds__(256) void oproj_kernel(
    const unsigned short* __restrict__ attn, const float* __restrict__ wo,
    const float* __restrict__ bo, float* out)
{
    gemm_body<1>(attn, wo, bo, (void*)out, 2, blockIdx.x * 128, blockIdx.y * 64);
}

// ---------------- Attention ----------------
// Grid: (64 q-groups of 16 rows, 32 bh). 256 thr = 4 waves.
// All 4 waves share the block's 16 q-rows; wave w covers K range [w*256, w*256+256)
// (4 tiles of 64). Fixed-max softmax (m == 0): p = exp(score), masked -> 0,
// fully-masked row -> p = 1 uniformly (== softmax of constant row).
// l is a plain sum reduced once at the end. Partial (o,l) combined in-block via LDS.
__global__ __launch_bounds__(256) void attn_kernel(
    const unsigned short* __restrict__ Qh, const unsigned short* __restrict__ Kh,
    const unsigned short* __restrict__ Vt, const int* __restrict__ mask,
    const float* __restrict__ shift, unsigned short* __restrict__ attnbuf)
{
    // Plds (9216 B) used during the loop; Olds (17408 B) used after a barrier. Aliased.
    __shared__ __align__(16) char smem[17408];
    __shared__ float Lw[4][16];
    auto Plds = reinterpret_cast<unsigned short(*)[16][72]>(smem);  // [w][row][col]
    auto Olds = reinterpret_cast<float(*)[16][68]>(smem);           // [w][row][dh]

    const int qg = blockIdx.x, bh = blockIdx.y;
    const int b_ = bh >> 4, h_ = bh & 15;
    const int t = threadIdx.x, w = t >> 6, lane = t & 63;
    const int g = lane >> 4, r = lane & 15;
    const int q0 = qg * 16;
    const int kstart = w * 256;

    const unsigned short* Qb = Qh + (size_t)bh * S_LEN * D_HEAD;
    const unsigned short* Kb = Kh + (size_t)bh * S_LEN * D_HEAD;
    const unsigned short* Vb = Vt + (size_t)bh * D_HEAD * S_LEN;
    const float* shb = shift + (size_t)bh * S_LEN * S_LEN;
    const int* mp = mask + (bh & (BATCH - 1)) * S_LEN;   // torch tiling: row = bh % B

    // Q fragments (B-operand): lane(r,g) holds Q[q0+r][g*8..g*8+7]
    short8 qf0 = *reinterpret_cast<const short8*>(&Qb[(size_t)(q0 + r) * D_HEAD + g * 8]);
    short8 qf1 = *reinterpret_cast<const short8*>(&Qb[(size_t)(q0 + r) * D_HEAD + 32 + g * 8]);
    const int mq = mp[q0 + r];
    const size_t shrow = (size_t)(q0 + r) * S_LEN;

    float l_loc = 0.f;
    f32x4 o_acc[4];
#pragma unroll
    for (int i = 0; i < 4; ++i) o_acc[i] = (f32x4){0.f, 0.f, 0.f, 0.f};

    // prefetch shift for tile 0
    f32x4 sh[4];
#pragma unroll
    for (int fn = 0; fn < 4; ++fn)
        sh[fn] = ldnt4(shb + shrow + kstart + fn * 16 + g * 4);

#pragma unroll
    for (int kt = 0; kt < 4; ++kt) {
        const int kbase = kstart + kt * 64;
        f32x4 shc[4];
#pragma unroll
        for (int fn = 0; fn < 4; ++fn) shc[fn] = sh[fn];
        if (kt < 3) {
#pragma unroll
            for (int fn = 0; fn < 4; ++fn)
                sh[fn] = ldnt4(shb + shrow + kbase + 64 + fn * 16 + g * 4);
        }

        // K fragments (A-operand): lane(r,g) holds K[kbase+fn*16+r][g*8..]
        short8 kf[8];
#pragma unroll
        for (int fn = 0; fn < 4; ++fn) {
            kf[2 * fn]     = *reinterpret_cast<const short8*>(&Kb[(size_t)(kbase + fn * 16 + r) * D_HEAD + g * 8]);
            kf[2 * fn + 1] = *reinterpret_cast<const short8*>(&Kb[(size_t)(kbase + fn * 16 + r) * D_HEAD + 32 + g * 8]);
        }

        // S^T = mfma(K,Q): lane(r,g) reg t4 = S[kbase+fn*16+g*4+t4][q0+r]
        float pexp[4][4];
#pragma unroll
        for (int fn = 0; fn < 4; ++fn) {
            f32x4 a = (f32x4){0.f, 0.f, 0.f, 0.f};
            a = __builtin_amdgcn_mfma_f32_16x16x32_bf16(kf[2 * fn], qf0, a, 0, 0, 0);
            a = __builtin_amdgcn_mfma_f32_16x16x32_bf16(kf[2 * fn + 1], qf1, a, 0, 0, 0);
            i32x4 mk = *reinterpret_cast<const i32x4*>(mp + kbase + fn * 16 + g * 4);
#pragma unroll
            for (int t4 = 0; t4 < 4; ++t4) {
                float e = __expf(fmaf(a[t4], 0.125f, shc[fn][t4]));
                float p = (mq & mk[t4]) ? e : 0.0f;
                if (mq == 0) p = 1.0f;          // fully-masked row -> uniform
                pexp[fn][t4] = p;
                l_loc += p;
            }
        }

        // hoist V loads above the LDS roundtrip (independent of P)
        short8 vfa[8];
#pragma unroll
        for (int df = 0; df < 4; ++df) {
            vfa[2 * df]     = *reinterpret_cast<const short8*>(&Vb[(size_t)(df * 16 + r) * S_LEN + kbase + g * 8]);
            vfa[2 * df + 1] = *reinterpret_cast<const short8*>(&Vb[(size_t)(df * 16 + r) * S_LEN + kbase + 32 + g * 8]);
        }

        // P -> LDS: lane(r,g) writes row r, cols fn*16+g*4..+3
#pragma unroll
        for (int fn = 0; fn < 4; ++fn) {
            ushort4 pk = { f2bf(pexp[fn][0]), f2bf(pexp[fn][1]), f2bf(pexp[fn][2]), f2bf(pexp[fn][3]) };
            *reinterpret_cast<ushort4*>(&Plds[w][r][fn * 16 + g * 4]) = pk;
        }
        asm volatile("s_waitcnt lgkmcnt(0)" ::: "memory");
        __builtin_amdgcn_sched_barrier(0);
        short8 pf0 = *reinterpret_cast<const short8*>(&Plds[w][r][g * 8]);
        short8 pf1 = *reinterpret_cast<const short8*>(&Plds[w][r][32 + g * 8]);
#pragma unroll
        for (int df = 0; df < 4; ++df) {
            o_acc[df] = __builtin_amdgcn_mfma_f32_16x16x32_bf16(pf0, vfa[2 * df], o_acc[df], 0, 0, 0);
            o_acc[df] = __builtin_amdgcn_mfma_f32_16x16x32_bf16(pf1, vfa[2 * df + 1], o_acc[df], 0, 0, 0);
        }
    }

    // per-row l: sum over the 4 g-lanes holding row r
    l_loc += __shfl_xor(l_loc, 16);
    l_loc += __shfl_xor(l_loc, 32);

    __syncthreads();   // all waves done reading their Plds before Olds overwrites

    if (g == 0) Lw[w][r] = l_loc;
#pragma unroll
    for (int df = 0; df < 4; ++df)
#pragma unroll
        for (int t4 = 0; t4 < 4; ++t4)
            Olds[w][g * 4 + t4][df * 16 + r] = o_acc[df][t4];

    __syncthreads();

    // combine 4 K-quarters: 1024 outputs, 4 per thread
    {
        const int col = t & 63;
        const int rb = t >> 6;
#pragma unroll
        for (int i = 0; i < 4; ++i) {
            int row = rb * 4 + i;
            float L = Lw[0][row] + Lw[1][row] + Lw[2][row] + Lw[3][row];
            float o = Olds[0][row][col] + Olds[1][row][col] + Olds[2][row][col] + Olds[3][row][col];
            attnbuf[(size_t)(b_ * S_LEN + q0 + row) * DMODEL + h_ * D_HEAD + col] = f2bf(o / L);
        }
    }
}

extern "C" void kernel_launch(void* const* d_in, const int* in_sizes, int n_in,
                              void* d_out, int out_size, void* d_ws, size_t ws_size,
                              hipStream_t stream)
{
    const float* q     = (const float*)d_in[0];
    const float* k     = (const float*)d_in[1];
    const float* v     = (const float*)d_in[2];
    const int*   mask  = (const int*)d_in[3];
    const float* shift = (const float*)d_in[4];
    const float* wq    = (const float*)d_in[5];
    const float* bq    = (const float*)d_in[6];
    const float* wk    = (const float*)d_in[7];
    const float* bk    = (const float*)d_in[8];
    const float* wv    = (const float*)d_in[9];
    const float* bv    = (const float*)d_in[10];
    const float* wo    = (const float*)d_in[11];
    const float* bo    = (const float*)d_in[12];
    float* out = (float*)d_out;

    // ws layout: Qh 4MB | Kh 4MB | Vt 4MB | attnbuf bf16 4MB  (16 MB total)
    const size_t nhalf = (size_t)N_BH * S_LEN * D_HEAD;   // 2M elems
    unsigned short* Qh = (unsigned short*)d_ws;
    unsigned short* Kh = Qh + nhalf;
    unsigned short* Vt = Kh + nhalf;
    unsigned short* attnbuf = Vt + nhalf;

    dim3 blk(256);
    qkv_kernel<<<dim3(16, 16, 3), blk, 0, stream>>>(q, k, v, wq, wk, wv, bq, bk, bv, Qh, Kh, Vt);
    attn_kernel<<<dim3(64, 32), blk, 0, stream>>>(Qh, Kh, Vt, mask, shift, attnbuf);
    oproj_kernel<<<dim3(16, 16), blk, 0, stream>>>(attnbuf, wo, bo, out);
}